// Round 1
// baseline (152.286 us; speedup 1.0000x reference)
//
#include <hip/hip_runtime.h>

// MPOLinear3: out[B,x,y,z] = sum_{a,b,c} x[B,a,b,c]*F[a,x]*M2[b,y]*L[c,z] + bias
// where F = sum_j first[a,j,x], M2 = sum_{r1,r2} middle[b,r1,r2,y], L = sum_j last[c,j,z].
// (Reference einsums sum rank axes independently -> pure Kronecker of 3 16x16 mats.)

#define LEG 16

// Prep: reduce cores into W (d_ws): WF[x*16+a]=F[a,x], WM[y*16+b]=M2[b,y], WL[z*16+c]=L[c,z]
__global__ __launch_bounds__(256) void mpo_prep(
    const float* __restrict__ first, const float* __restrict__ middle,
    const float* __restrict__ last, float* __restrict__ W)
{
    __shared__ float red[256];
    const int t = threadIdx.x;
    const int blk = blockIdx.x;
    if (blk == 0) {
        const int xo = t >> 4, a = t & 15;
        float s = 0.f;
        #pragma unroll 8
        for (int j = 0; j < 64; ++j) s += first[a * 1024 + j * 16 + xo];
        W[t] = s;                       // WF[xo*16 + a]
    } else if (blk == 1) {
        const int z = t >> 4, c = t & 15;
        float s = 0.f;
        #pragma unroll 8
        for (int j = 0; j < 64; ++j) s += last[c * 1024 + j * 16 + z];
        W[512 + t] = s;                 // WL[z*16 + c]
    } else {
        const int b = blk - 2;          // 0..15
        const int g = t >> 4, y = t & 15;
        float s = 0.f;
        for (int r1 = g; r1 < 64; r1 += 16) {
            const float* p = middle + (size_t)b * 65536 + (size_t)r1 * 1024 + y;
            #pragma unroll 8
            for (int r2 = 0; r2 < 64; ++r2) s += p[r2 * 16];
        }
        red[t] = s;
        __syncthreads();
        if (t < 16) {
            float tot = 0.f;
            #pragma unroll
            for (int g2 = 0; g2 < 16; ++g2) tot += red[g2 * 16 + t];
            W[256 + t * 16 + b] = tot;  // WM[y*16 + b]
        }
    }
}

// Main: one block (256 threads) per batch row. 3 mode products via LDS ping-pong.
__global__ __launch_bounds__(256, 4) void mpo_main(
    const float* __restrict__ x, const float* __restrict__ W,
    const float* __restrict__ bias, float* __restrict__ out)
{
    __shared__ float bufA[4352];   // x row [a][b][c] flat; later stage-2 out, stride 17
    __shared__ float bufB[4224];   // stage-1 out [xo][b*16+c], stride 264 (pad vs 256)

    const int t = threadIdx.x;
    const size_t row = blockIdx.x;
    const float* xrow = x + row * 4096;
    float* orow = out + row * 4096;

    // bias for this thread's 16 output columns (t*16 .. t*16+15), held in regs
    float4 bv[4];
    #pragma unroll
    for (int i = 0; i < 4; ++i)
        bv[i] = *(const float4*)(bias + t * 16 + i * 4);

    // stage x row into LDS (coalesced float4)
    #pragma unroll
    for (int i = 0; i < 4; ++i) {
        float4 v = *(const float4*)(xrow + (i * 256 + t) * 4);
        *(float4*)(bufA + (i * 256 + t) * 4) = v;
    }
    __syncthreads();

    const float* WF = W;        // [x][a]
    const float* WM = W + 256;  // [y][b]
    const float* WL = W + 512;  // [z][c]

    // ---- Stage 1: t1[xo][b][c] = sum_a x[a][b][c]*F[a][xo]; thread owns (b,c)=t
    {
        float xa[16];
        #pragma unroll
        for (int a = 0; a < 16; ++a) xa[a] = bufA[a * 256 + t];
        #pragma unroll
        for (int q = 0; q < 4; ++q) {
            float acc[4] = {0.f, 0.f, 0.f, 0.f};
            #pragma unroll
            for (int a = 0; a < 16; ++a) {
                #pragma unroll
                for (int j = 0; j < 4; ++j)
                    acc[j] += xa[a] * WF[(q * 4 + j) * 16 + a];
            }
            #pragma unroll
            for (int j = 0; j < 4; ++j)
                bufB[(q * 4 + j) * 264 + t] = acc[j];
        }
    }
    __syncthreads();

    // ---- Stage 2: t2[xo][y][c] = sum_b t1[xo][b][c]*M2[b][y]; thread owns (xo,c)
    {
        const int x_ = t >> 4, c_ = t & 15;
        float tb[16];
        #pragma unroll
        for (int b = 0; b < 16; ++b) tb[b] = bufB[x_ * 264 + b * 16 + c_];
        #pragma unroll
        for (int q = 0; q < 4; ++q) {
            float acc[4] = {0.f, 0.f, 0.f, 0.f};
            #pragma unroll
            for (int b = 0; b < 16; ++b) {
                #pragma unroll
                for (int j = 0; j < 4; ++j)
                    acc[j] += tb[b] * WM[(q * 4 + j) * 16 + b];
            }
            #pragma unroll
            for (int j = 0; j < 4; ++j)
                bufA[(x_ * 16 + q * 4 + j) * 17 + c_] = acc[j];   // [p=(xo,y)] stride 17
        }
    }
    __syncthreads();

    // ---- Stage 3: out[xo][y][z] = sum_c t2[xo][y][c]*L[c][z] + bias; thread owns p=(xo,y)=t
    {
        float tc[16];
        #pragma unroll
        for (int c = 0; c < 16; ++c) tc[c] = bufA[t * 17 + c];
        #pragma unroll
        for (int q = 0; q < 4; ++q) {
            float acc[4] = {bv[q].x, bv[q].y, bv[q].z, bv[q].w};
            #pragma unroll
            for (int c = 0; c < 16; ++c) {
                #pragma unroll
                for (int j = 0; j < 4; ++j)
                    acc[j] += tc[c] * WL[(q * 4 + j) * 16 + c];
            }
            float4 o;
            o.x = acc[0]; o.y = acc[1]; o.z = acc[2]; o.w = acc[3];
            *(float4*)(orow + t * 16 + q * 4) = o;
        }
    }
}

extern "C" void kernel_launch(void* const* d_in, const int* in_sizes, int n_in,
                              void* d_out, int out_size, void* d_ws, size_t ws_size,
                              hipStream_t stream) {
    const float* x      = (const float*)d_in[0];
    const float* first  = (const float*)d_in[1];
    const float* middle = (const float*)d_in[2];
    const float* last   = (const float*)d_in[3];
    const float* bias   = (const float*)d_in[4];
    float* out = (float*)d_out;
    float* W   = (float*)d_ws;          // 768 floats: WF | WM | WL

    const int Brows = in_sizes[0] / 4096;

    hipLaunchKernelGGL(mpo_prep, dim3(18), dim3(256), 0, stream,
                       first, middle, last, W);
    hipLaunchKernelGGL(mpo_main, dim3(Brows), dim3(256), 0, stream,
                       x, W, bias, out);
}